// Round 2
// baseline (116.234 us; speedup 1.0000x reference)
//
#include <hip/hip_runtime.h>
#include <math.h>
#include <stdint.h>

#define IN_DIM  256
#define OUT_DIM 256
#define NROWS   68     // G + K
#define NT      71     // knot count
#define BATCH   512

// ---- Kernel 0: zero the output (enables cross-chunk atomic reduction,
//      removing all workspace usage) ----
__global__ __launch_bounds__(256) void zero_out_kernel(float* __restrict__ out) {
  const int q = blockIdx.x * 256 + threadIdx.x;   // float4 index, 32768 total
  ((float4*)out)[q] = make_float4(0.f, 0.f, 0.f, 0.f);
}

// ---- Kernel 1: gather-accumulate straight from fp32 weights, no workspace.
//      Block = 8 batch rows x 32 channels (L1/MSHR dedup across the 8 b's).
//      Wave = one channel per pass: 64 lanes x float4 = full 256-o row. ----
__global__ __launch_bounds__(256) void kan_gather_fp32_kernel(
    const float* __restrict__ x, const float* __restrict__ w,
    const float* __restrict__ t, float* __restrict__ out) {
  __shared__ float  lt[NT];
  __shared__ float4 nA[32][8];    // N0..N3 per (local c, local b)
  __shared__ float  sA[32][8];    // silu(x)
  __shared__ int    bA[32][8];    // base row (i-3)
  __shared__ float  red[4][2048]; // per-wave partials: [wave][b*256 + o]

  const int tid = threadIdx.x;
  const unsigned bid = blockIdx.x;
  // cchunk = bid&7 -> XCD affinity (dispatch round-robins bid%8): each XCD's
  // L2 holds only its 32-channel fp32 slice (68*32*1KB = 2.2 MB < 4 MB).
  const int cchunk = bid & 7;
  const int bgroup = bid >> 3;    // 64 groups of 8 batch rows

  if (tid < NT) lt[tid] = t[tid];
  __syncthreads();

  // ---- Phase 1: basis for 8 b x 32 c; one (b,c) pair per thread ----
  {
    const int bb = tid >> 5;
    const int cl = tid & 31;
    const float xv = x[(size_t)(bgroup * 8 + bb) * IN_DIM + cchunk * 32 + cl];
    int i = 3 + (int)floorf((xv + 1.0f) * 32.0f);
    i = i < 3 ? 3 : (i > 66 ? 66 : i);
    while (i > 3 && xv < lt[i]) --i;
    while (i < 66 && xv >= lt[i + 1]) ++i;

    float N0 = 1.f, N1 = 0.f, N2 = 0.f, N3 = 0.f;
    { // p = 1
      const float l1 = xv - lt[i];
      const float r1 = lt[i + 1] - xv;
      const float tp = N0 / (r1 + l1);
      N1 = l1 * tp; N0 = r1 * tp;
    }
    { // p = 2
      const float l1 = xv - lt[i];
      const float l2 = xv - lt[i - 1];
      const float r1 = lt[i + 1] - xv;
      const float r2 = lt[i + 2] - xv;
      float saved = 0.f;
      const float tp0 = N0 / (r1 + l2);
      const float n0 = saved + r1 * tp0; saved = l2 * tp0;
      const float tp1 = N1 / (r2 + l1);
      const float n1 = saved + r2 * tp1; saved = l1 * tp1;
      N0 = n0; N1 = n1; N2 = saved;
    }
    { // p = 3
      const float l1 = xv - lt[i];
      const float l2 = xv - lt[i - 1];
      const float l3 = xv - lt[i - 2];
      const float r1 = lt[i + 1] - xv;
      const float r2 = lt[i + 2] - xv;
      const float r3 = lt[i + 3] - xv;
      float saved = 0.f;
      const float tp0 = N0 / (r1 + l3);
      const float n0 = saved + r1 * tp0; saved = l3 * tp0;
      const float tp1 = N1 / (r2 + l2);
      const float n1 = saved + r2 * tp1; saved = l2 * tp1;
      const float tp2 = N2 / (r3 + l1);
      const float n2 = saved + r3 * tp2; saved = l1 * tp2;
      N0 = n0; N1 = n1; N2 = n2; N3 = saved;
    }
    nA[cl][bb] = make_float4(N0, N1, N2, N3);
    sA[cl][bb] = xv / (1.0f + expf(-xv));
    bA[cl][bb] = i - 3;
  }
  __syncthreads();

  // ---- Phase 2: wave wv handles channels wv*8 .. wv*8+7, one per pass.
  //      lane = float4 slot over the 256 outputs. The 8 b's row reads for
  //      one channel issue back-to-back -> duplicates merge in L1/MSHR. ----
  const int wv   = tid >> 6;
  const int lane = tid & 63;
  const float4* wf = (const float4*)w;   // w[row][c][o], row stride 16384 f4

  float acc[8][4];
  #pragma unroll
  for (int b = 0; b < 8; ++b) {
    acc[b][0] = 0.f; acc[b][1] = 0.f; acc[b][2] = 0.f; acc[b][3] = 0.f;
  }

  for (int pp = 0; pp < 8; ++pp) {
    const int cl = wv * 8 + pp;                       // local c, 0..31
    const uint32_t cb = (uint32_t)((cchunk * 32 + cl) * 64 + lane);
    const float4 q4 = wf[cb + 67u * 16384u];          // silu row: once per c
    #pragma unroll
    for (int b = 0; b < 8; ++b) {
      const float4 yv = nA[cl][b];
      const float  ys = sA[cl][b];
      const uint32_t rb = cb + ((uint32_t)bA[cl][b] * 16384u);
      const float4 q0 = wf[rb];
      const float4 q1 = wf[rb + 16384u];
      const float4 q2 = wf[rb + 32768u];
      const float4 q3 = wf[rb + 49152u];
      acc[b][0] += yv.x * q0.x + yv.y * q1.x + yv.z * q2.x + yv.w * q3.x + ys * q4.x;
      acc[b][1] += yv.x * q0.y + yv.y * q1.y + yv.z * q2.y + yv.w * q3.y + ys * q4.y;
      acc[b][2] += yv.x * q0.z + yv.y * q1.z + yv.z * q2.z + yv.w * q3.z + ys * q4.z;
      acc[b][3] += yv.x * q0.w + yv.y * q1.w + yv.z * q2.w + yv.w * q3.w + ys * q4.w;
    }
  }

  // ---- Phase 3: LDS-reduce the 4 waves, atomic-add chunk partial to out ----
  #pragma unroll
  for (int b = 0; b < 8; ++b) {
    float4 v = make_float4(acc[b][0], acc[b][1], acc[b][2], acc[b][3]);
    *(float4*)&red[wv][b * 256 + lane * 4] = v;
  }
  __syncthreads();
  {
    const int b  = tid >> 5;         // local batch row
    const int oo = tid & 31;         // 8-float slot
    float s[8] = {0.f, 0.f, 0.f, 0.f, 0.f, 0.f, 0.f, 0.f};
    #pragma unroll
    for (int w2 = 0; w2 < 4; ++w2) {
      const float* rr = &red[w2][b * 256 + oo * 8];
      #pragma unroll
      for (int j = 0; j < 8; ++j) s[j] += rr[j];
    }
    float* dst = out + ((size_t)(bgroup * 8 + b)) * OUT_DIM + oo * 8;
    #pragma unroll
    for (int j = 0; j < 8; ++j) unsafeAtomicAdd(dst + j, s[j]);  // global_atomic_add_f32
  }
}

extern "C" void kernel_launch(void* const* d_in, const int* in_sizes, int n_in,
                              void* d_out, int out_size, void* d_ws, size_t ws_size,
                              hipStream_t stream) {
  const float* x = (const float*)d_in[0];
  const float* w = (const float*)d_in[1];
  const float* t = (const float*)d_in[2];
  float* out = (float*)d_out;
  (void)d_ws; (void)ws_size;   // workspace deliberately untouched (poison-fill probe)
  zero_out_kernel<<<BATCH * OUT_DIM / 4 / 256, 256, 0, stream>>>(out);
  kan_gather_fp32_kernel<<<BATCH / 8 * 8, 256, 0, stream>>>(x, w, t, out);
}

// Round 3
// 102.316 us; speedup vs baseline: 1.1360x; 1.1360x over previous
//
#include <hip/hip_runtime.h>
#include <math.h>
#include <stdint.h>

#define IN_DIM  256
#define OUT_DIM 256
#define NROWS   68     // G + K
#define NT      71     // knot count
#define BATCH   512

// ---- Kernel 0: zero the output (cross-chunk atomic reduction target) ----
__global__ __launch_bounds__(256) void zero_out_kernel(float* __restrict__ out) {
  const int q = blockIdx.x * 256 + threadIdx.x;   // float4 index, 32768 total
  ((float4*)out)[q] = make_float4(0.f, 0.f, 0.f, 0.f);
}

// ---- Kernel 1: gather-accumulate from fp32 weights.
//      Block = 8 batch rows x 32 channels x 128 outputs (o-split x2).
//      Grid 1024 -> 4 blocks/CU; explicit 2-deep load pipeline over b
//      keeps ~10 KB/wave of scattered loads in flight (latency hiding). ----
__global__ __launch_bounds__(256, 4) void kan_gather_fp32_kernel(
    const float* __restrict__ x, const float* __restrict__ w,
    const float* __restrict__ t, float* __restrict__ out) {
  __shared__ float  lt[NT];
  __shared__ float4 nA[32][8];     // N0..N3 per (local c, local b)
  __shared__ float  sA[32][8];     // silu(x)
  __shared__ int    bA[32][8];     // base row (i-3)
  __shared__ float4 red4[4][256];  // per-wave partials: [wave][b*32 + ol]

  const int tid = threadIdx.x;
  const unsigned bid = blockIdx.x;
  // cchunk = bid&7 -> XCD affinity (dispatch round-robins bid%8).
  const int cchunk = bid & 7;
  const int bgroup = (bid >> 3) & 63;   // 64 groups of 8 batch rows
  const int ohalf  = bid >> 9;          // 0/1: which 128-output half

  if (tid < NT) lt[tid] = t[tid];
  __syncthreads();

  // ---- Phase 1: basis for 8 b x 32 c; one (b,c) pair per thread ----
  {
    const int bb = tid >> 5;
    const int cl = tid & 31;
    const float xv = x[(size_t)(bgroup * 8 + bb) * IN_DIM + cchunk * 32 + cl];
    int i = 3 + (int)floorf((xv + 1.0f) * 32.0f);
    i = i < 3 ? 3 : (i > 66 ? 66 : i);
    while (i > 3 && xv < lt[i]) --i;
    while (i < 66 && xv >= lt[i + 1]) ++i;

    float N0 = 1.f, N1 = 0.f, N2 = 0.f, N3 = 0.f;
    { // p = 1
      const float l1 = xv - lt[i];
      const float r1 = lt[i + 1] - xv;
      const float tp = N0 / (r1 + l1);
      N1 = l1 * tp; N0 = r1 * tp;
    }
    { // p = 2
      const float l1 = xv - lt[i];
      const float l2 = xv - lt[i - 1];
      const float r1 = lt[i + 1] - xv;
      const float r2 = lt[i + 2] - xv;
      float saved = 0.f;
      const float tp0 = N0 / (r1 + l2);
      const float n0 = saved + r1 * tp0; saved = l2 * tp0;
      const float tp1 = N1 / (r2 + l1);
      const float n1 = saved + r2 * tp1; saved = l1 * tp1;
      N0 = n0; N1 = n1; N2 = saved;
    }
    { // p = 3
      const float l1 = xv - lt[i];
      const float l2 = xv - lt[i - 1];
      const float l3 = xv - lt[i - 2];
      const float r1 = lt[i + 1] - xv;
      const float r2 = lt[i + 2] - xv;
      const float r3 = lt[i + 3] - xv;
      float saved = 0.f;
      const float tp0 = N0 / (r1 + l3);
      const float n0 = saved + r1 * tp0; saved = l3 * tp0;
      const float tp1 = N1 / (r2 + l2);
      const float n1 = saved + r2 * tp1; saved = l2 * tp1;
      const float tp2 = N2 / (r3 + l1);
      const float n2 = saved + r3 * tp2; saved = l1 * tp2;
      N0 = n0; N1 = n1; N2 = n2; N3 = saved;
    }
    nA[cl][bb] = make_float4(N0, N1, N2, N3);
    sA[cl][bb] = xv / (1.0f + expf(-xv));
    bA[cl][bb] = i - 3;
  }
  __syncthreads();

  // ---- Phase 2: wave = 2 channels/pass (half-wave each, 32 lanes x float4
  //      = 128 outputs), 4 passes -> 8 channels/wave. Ping-pong A/B register
  //      buffers keep 2 b's of scattered row loads in flight. ----
  const int wv   = tid >> 6;
  const int lane = tid & 63;
  const int half = lane >> 5;
  const int ol   = lane & 31;
  const float4* wf = (const float4*)w;   // row stride 16384 float4

  float4 acc[8];
  #pragma unroll
  for (int b = 0; b < 8; ++b) acc[b] = make_float4(0.f, 0.f, 0.f, 0.f);

  for (int pp = 0; pp < 4; ++pp) {
    const int cl = wv * 8 + pp * 2 + half;           // local c, 0..31
    const uint32_t cb = (uint32_t)((cchunk * 32 + cl) * 64 + ohalf * 32 + ol);
    const float4 q4 = wf[cb + 67u * 16384u];         // silu row: once per c

#define LD(P0, P1, P2, P3, bb)                                          \
    { const uint32_t rb = cb + (uint32_t)bA[cl][bb] * 16384u;           \
      P0 = wf[rb]; P1 = wf[rb + 16384u];                                \
      P2 = wf[rb + 32768u]; P3 = wf[rb + 49152u]; }
#define FM(P0, P1, P2, P3, bb)                                          \
    { const float4 yv = nA[cl][bb]; const float ys = sA[cl][bb];        \
      acc[bb].x += yv.x*P0.x + yv.y*P1.x + yv.z*P2.x + yv.w*P3.x + ys*q4.x; \
      acc[bb].y += yv.x*P0.y + yv.y*P1.y + yv.z*P2.y + yv.w*P3.y + ys*q4.y; \
      acc[bb].z += yv.x*P0.z + yv.y*P1.z + yv.z*P2.z + yv.w*P3.z + ys*q4.z; \
      acc[bb].w += yv.x*P0.w + yv.y*P1.w + yv.z*P2.w + yv.w*P3.w + ys*q4.w; }

    float4 A0, A1, A2, A3, B0, B1, B2, B3;
    LD(A0, A1, A2, A3, 0)
    LD(B0, B1, B2, B3, 1)
    FM(A0, A1, A2, A3, 0)
    LD(A0, A1, A2, A3, 2)
    FM(B0, B1, B2, B3, 1)
    LD(B0, B1, B2, B3, 3)
    FM(A0, A1, A2, A3, 2)
    LD(A0, A1, A2, A3, 4)
    FM(B0, B1, B2, B3, 3)
    LD(B0, B1, B2, B3, 5)
    FM(A0, A1, A2, A3, 4)
    LD(A0, A1, A2, A3, 6)
    FM(B0, B1, B2, B3, 5)
    LD(B0, B1, B2, B3, 7)
    FM(A0, A1, A2, A3, 6)
    FM(B0, B1, B2, B3, 7)
#undef LD
#undef FM
  }

  // fold the two half-waves (partner lane holds the other channel's partial)
  #pragma unroll
  for (int b = 0; b < 8; ++b) {
    acc[b].x += __shfl_xor(acc[b].x, 32);
    acc[b].y += __shfl_xor(acc[b].y, 32);
    acc[b].z += __shfl_xor(acc[b].z, 32);
    acc[b].w += __shfl_xor(acc[b].w, 32);
  }
  if (half == 0) {
    #pragma unroll
    for (int b = 0; b < 8; ++b) red4[wv][b * 32 + ol] = acc[b];
  }
  __syncthreads();

  // ---- Phase 3: sum the 4 waves, one atomic float4-quad per thread ----
  {
    const int b   = tid >> 5;        // local batch row
    const int ol2 = tid & 31;        // float4 slot within the 128-o half
    const float4 a0 = red4[0][b * 32 + ol2];
    const float4 a1 = red4[1][b * 32 + ol2];
    const float4 a2 = red4[2][b * 32 + ol2];
    const float4 a3 = red4[3][b * 32 + ol2];
    float4 s;
    s.x = (a0.x + a1.x) + (a2.x + a3.x);
    s.y = (a0.y + a1.y) + (a2.y + a3.y);
    s.z = (a0.z + a1.z) + (a2.z + a3.z);
    s.w = (a0.w + a1.w) + (a2.w + a3.w);
    float* dst = out + ((size_t)(bgroup * 8 + b)) * OUT_DIM + ohalf * 128 + ol2 * 4;
    unsafeAtomicAdd(dst + 0, s.x);
    unsafeAtomicAdd(dst + 1, s.y);
    unsafeAtomicAdd(dst + 2, s.z);
    unsafeAtomicAdd(dst + 3, s.w);
  }
}

extern "C" void kernel_launch(void* const* d_in, const int* in_sizes, int n_in,
                              void* d_out, int out_size, void* d_ws, size_t ws_size,
                              hipStream_t stream) {
  const float* x = (const float*)d_in[0];
  const float* w = (const float*)d_in[1];
  const float* t = (const float*)d_in[2];
  float* out = (float*)d_out;
  (void)d_ws; (void)ws_size;   // fills proven unconditional; ws unused
  zero_out_kernel<<<BATCH * OUT_DIM / 4 / 256, 256, 0, stream>>>(out);
  kan_gather_fp32_kernel<<<1024, 256, 0, stream>>>(x, w, t, out);
}

// Round 4
// 97.379 us; speedup vs baseline: 1.1936x; 1.0507x over previous
//
#include <hip/hip_runtime.h>
#include <math.h>
#include <stdint.h>

#define IN_DIM  256
#define OUT_DIM 256
#define NROWS   68     // G + K
#define NT      71     // knot count
#define BATCH   512
#define W_ELEMS (NROWS * IN_DIM * OUT_DIM)   // 4,456,448
#define PART_FLOATS (8 * BATCH * OUT_DIM)    // 4 MB of c-chunk partials

// ---- Kernel A: convert w fp32 -> packed bf16 pairs (streaming, ~4.5 us) ----
__device__ __forceinline__ uint32_t bf16_rne(float f) {
  uint32_t u = __builtin_bit_cast(uint32_t, f);
  return (u + 0x7fffu + ((u >> 16) & 1u)) >> 16;   // finite inputs only
}

__global__ __launch_bounds__(256) void cvt_kernel(const float* __restrict__ w,
                                                  uint32_t* __restrict__ wb) {
  const int base = (blockIdx.x * 256 + threadIdx.x) * 8;   // 8 floats / thread
  const float4 a = *(const float4*)(w + base);
  const float4 b = *(const float4*)(w + base + 4);
  uint4 o;
  o.x = bf16_rne(a.x) | (bf16_rne(a.y) << 16);
  o.y = bf16_rne(a.z) | (bf16_rne(a.w) << 16);
  o.z = bf16_rne(b.x) | (bf16_rne(b.y) << 16);
  o.w = bf16_rne(b.z) | (bf16_rne(b.w) << 16);
  *(uint4*)(wb + base / 2) = o;
}

// ---- Kernel B: bf16 gather-accumulate.
//      Block = 4 batch rows x 32 channels (grid 1024 -> 4 blocks/CU via
//      __launch_bounds__(256,4)); half-wave = one channel (32 lanes x uint4 =
//      full 256-o bf16 row); explicit 2-deep A/B ping-pong over b. ----
__device__ __forceinline__ void fma8(const uint4 q, const float y, float* acc) {
  acc[0] += y * __builtin_bit_cast(float, q.x << 16);
  acc[1] += y * __builtin_bit_cast(float, q.x & 0xffff0000u);
  acc[2] += y * __builtin_bit_cast(float, q.y << 16);
  acc[3] += y * __builtin_bit_cast(float, q.y & 0xffff0000u);
  acc[4] += y * __builtin_bit_cast(float, q.z << 16);
  acc[5] += y * __builtin_bit_cast(float, q.z & 0xffff0000u);
  acc[6] += y * __builtin_bit_cast(float, q.w << 16);
  acc[7] += y * __builtin_bit_cast(float, q.w & 0xffff0000u);
}

__global__ __launch_bounds__(256, 4) void kan_gather_kernel(
    const float* __restrict__ x, const uint4* __restrict__ wp,
    const float* __restrict__ t, float* __restrict__ part) {
  __shared__ float  lt[NT];
  __shared__ float4 nA[32][4];    // N0..N3 per (local c, local b)
  __shared__ float  sA[32][4];    // silu(x)
  __shared__ int    bA[32][4];    // base row (i-3)
  __shared__ float  red[4][1024]; // per-wave partials: [wave][b*256 + o]

  const int tid = threadIdx.x;
  const unsigned bid = blockIdx.x;
  // cchunk = bid&7 -> XCD affinity (dispatch round-robins bid%8): each XCD's
  // L2 holds only its 32-channel bf16 slice (68*32*512B = 1.1 MB).
  const int cchunk = bid & 7;
  const int bgroup = bid >> 3;    // 128 groups of 4 batch rows

  if (tid < NT) lt[tid] = t[tid];
  __syncthreads();

  // ---- Phase 1: basis for 4 b x 32 c; one (b,c) pair per thread ----
  if (tid < 128) {
    const int bb = tid >> 5;
    const int cl = tid & 31;
    const float xv = x[(size_t)(bgroup * 4 + bb) * IN_DIM + cchunk * 32 + cl];
    int i = 3 + (int)floorf((xv + 1.0f) * 32.0f);
    i = i < 3 ? 3 : (i > 66 ? 66 : i);
    while (i > 3 && xv < lt[i]) --i;
    while (i < 66 && xv >= lt[i + 1]) ++i;

    float N0 = 1.f, N1 = 0.f, N2 = 0.f, N3 = 0.f;
    { // p = 1
      const float l1 = xv - lt[i];
      const float r1 = lt[i + 1] - xv;
      const float tp = N0 / (r1 + l1);
      N1 = l1 * tp; N0 = r1 * tp;
    }
    { // p = 2
      const float l1 = xv - lt[i];
      const float l2 = xv - lt[i - 1];
      const float r1 = lt[i + 1] - xv;
      const float r2 = lt[i + 2] - xv;
      float saved = 0.f;
      const float tp0 = N0 / (r1 + l2);
      const float n0 = saved + r1 * tp0; saved = l2 * tp0;
      const float tp1 = N1 / (r2 + l1);
      const float n1 = saved + r2 * tp1; saved = l1 * tp1;
      N0 = n0; N1 = n1; N2 = saved;
    }
    { // p = 3
      const float l1 = xv - lt[i];
      const float l2 = xv - lt[i - 1];
      const float l3 = xv - lt[i - 2];
      const float r1 = lt[i + 1] - xv;
      const float r2 = lt[i + 2] - xv;
      const float r3 = lt[i + 3] - xv;
      float saved = 0.f;
      const float tp0 = N0 / (r1 + l3);
      const float n0 = saved + r1 * tp0; saved = l3 * tp0;
      const float tp1 = N1 / (r2 + l2);
      const float n1 = saved + r2 * tp1; saved = l2 * tp1;
      const float tp2 = N2 / (r3 + l1);
      const float n2 = saved + r3 * tp2; saved = l1 * tp2;
      N0 = n0; N1 = n1; N2 = n2; N3 = saved;
    }
    nA[cl][bb] = make_float4(N0, N1, N2, N3);
    sA[cl][bb] = xv / (1.0f + expf(-xv));
    bA[cl][bb] = i - 3;
  }
  __syncthreads();

  // ---- Phase 2: wave = 2 channels/pass (half-wave each), 4 passes.
  //      Per channel: silu row + 4 b's x 4 rows, 2-deep ping-pong over b. ----
  const int wv   = tid >> 6;
  const int lane = tid & 63;
  const int half = lane >> 5;
  const int ol   = lane & 31;

  float acc[4][8];
  #pragma unroll
  for (int b = 0; b < 4; ++b) {
    #pragma unroll
    for (int j = 0; j < 8; ++j) acc[b][j] = 0.f;
  }

  for (int pp = 0; pp < 4; ++pp) {
    const int cl = wv * 8 + pp * 2 + half;            // local c, 0..31
    const uint32_t cb = (uint32_t)((cchunk * 32 + cl) * 32 + ol);
    const uint4 q4 = wp[cb + 67u * 8192u];            // silu row, issued first

    // hoist row bases + coefficients into registers (FM groups are LDS-free)
    const int r0 = bA[cl][0], r1 = bA[cl][1], r2 = bA[cl][2], r3 = bA[cl][3];
    const float4 y0 = nA[cl][0], y1 = nA[cl][1], y2 = nA[cl][2], y3 = nA[cl][3];
    const float  s0 = sA[cl][0], s1 = sA[cl][1], s2 = sA[cl][2], s3 = sA[cl][3];

#define LD(P0, P1, P2, P3, RB)                                          \
    { const uint32_t rb = cb + (uint32_t)(RB) * 8192u;                  \
      P0 = wp[rb]; P1 = wp[rb +  8192u];                                \
      P2 = wp[rb + 16384u]; P3 = wp[rb + 24576u]; }
#define FM(P0, P1, P2, P3, YV, YS, bb)                                  \
    { fma8(P0, YV.x, acc[bb]); fma8(P1, YV.y, acc[bb]);                 \
      fma8(P2, YV.z, acc[bb]); fma8(P3, YV.w, acc[bb]);                 \
      fma8(q4, YS,   acc[bb]); }

    uint4 A0, A1, A2, A3, B0, B1, B2, B3;
    LD(A0, A1, A2, A3, r0)
    LD(B0, B1, B2, B3, r1)
    FM(A0, A1, A2, A3, y0, s0, 0)
    LD(A0, A1, A2, A3, r2)
    FM(B0, B1, B2, B3, y1, s1, 1)
    LD(B0, B1, B2, B3, r3)
    FM(A0, A1, A2, A3, y2, s2, 2)
    FM(B0, B1, B2, B3, y3, s3, 3)
#undef LD
#undef FM
  }

  // fold the two half-waves (partner lane holds the pass's other channel)
  #pragma unroll
  for (int b = 0; b < 4; ++b) {
    #pragma unroll
    for (int j = 0; j < 8; ++j)
      acc[b][j] += __shfl_xor(acc[b][j], 32);
  }
  if (half == 0) {
    #pragma unroll
    for (int b = 0; b < 4; ++b) {
      *(float4*)&red[wv][b * 256 + ol * 8]     = make_float4(acc[b][0], acc[b][1], acc[b][2], acc[b][3]);
      *(float4*)&red[wv][b * 256 + ol * 8 + 4] = make_float4(acc[b][4], acc[b][5], acc[b][6], acc[b][7]);
    }
  }
  __syncthreads();

  // ---- Phase 3: sum the 4 waves, store c-chunk partial (streaming) ----
  {
    const int b  = tid >> 6;        // local batch row
    const int o4 = tid & 63;        // float4 slot over 256 outputs
    const float4 a0 = *(const float4*)&red[0][b * 256 + o4 * 4];
    const float4 a1 = *(const float4*)&red[1][b * 256 + o4 * 4];
    const float4 a2 = *(const float4*)&red[2][b * 256 + o4 * 4];
    const float4 a3 = *(const float4*)&red[3][b * 256 + o4 * 4];
    float4 s;
    s.x = (a0.x + a1.x) + (a2.x + a3.x);
    s.y = (a0.y + a1.y) + (a2.y + a3.y);
    s.z = (a0.z + a1.z) + (a2.z + a3.z);
    s.w = (a0.w + a1.w) + (a2.w + a3.w);
    *(float4*)(part + ((size_t)cchunk * BATCH + bgroup * 4 + b) * OUT_DIM + o4 * 4) = s;
  }
}

// ---- Kernel C: reduce the 8 c-chunk partials into out ----
__global__ __launch_bounds__(256) void reduce_kernel(const float* __restrict__ part,
                                                     float* __restrict__ out) {
  const int q = blockIdx.x * 256 + threadIdx.x;   // float4 index, 32768 total
  const int S = BATCH * OUT_DIM / 4;              // float4 stride per slice
  const float4* p = (const float4*)part;
  float4 s = p[q];
  #pragma unroll
  for (int k = 1; k < 8; ++k) {
    const float4 a = p[q + k * S];
    s.x += a.x; s.y += a.y; s.z += a.z; s.w += a.w;
  }
  ((float4*)out)[q] = s;
}

extern "C" void kernel_launch(void* const* d_in, const int* in_sizes, int n_in,
                              void* d_out, int out_size, void* d_ws, size_t ws_size,
                              hipStream_t stream) {
  const float* x = (const float*)d_in[0];
  const float* w = (const float*)d_in[1];
  const float* t = (const float*)d_in[2];
  float* out  = (float*)d_out;
  float* part = (float*)d_ws;                       // 4 MB of partials
  uint32_t* wb = (uint32_t*)d_ws + PART_FLOATS;     // bf16 weights after
  cvt_kernel<<<W_ELEMS / (256 * 8), 256, 0, stream>>>(w, wb);
  kan_gather_kernel<<<1024, 256, 0, stream>>>(x, (const uint4*)wb, t, part);
  reduce_kernel<<<BATCH * OUT_DIM / 4 / 256, 256, 0, stream>>>(part, out);
}